// Round 7
// baseline (541.599 us; speedup 1.0000x reference)
//
#include <hip/hip_runtime.h>
#include <hip/hip_bf16.h>
#include <math.h>

#define NROWS 65536
#define DIN   512
#define H1    256
#define H2    128
#define K3DIM 384
#define O3    64

typedef short  short8  __attribute__((ext_vector_type(8)));
typedef float  f32x4   __attribute__((ext_vector_type(4)));
typedef unsigned short u16x4 __attribute__((ext_vector_type(4)));

// fp32 -> bf16 bits, round-to-nearest-even
__device__ __forceinline__ unsigned short f2bf(float f) {
    union { float f; unsigned int i; } v; v.f = f;
    unsigned int r = (v.i + 0x7fffu + ((v.i >> 16) & 1u)) >> 16;
    return (unsigned short)r;
}
// bf16 bits -> fp32 (exact)
__device__ __forceinline__ float bf2f(unsigned short u) {
    union { unsigned int i; float f; } v; v.i = ((unsigned int)u) << 16;
    return v.f;
}

// ---------------------------------------------------------------- K0: all three W -> W^T bf16 (one launch)
__global__ void transpose3_kernel(const float* __restrict__ W1, const float* __restrict__ W2,
                                  const float* __restrict__ W3,
                                  unsigned short* __restrict__ w1t, unsigned short* __restrict__ w2t,
                                  unsigned short* __restrict__ w3t) {
    int idx = blockIdx.x * 256 + threadIdx.x;
    const int n1 = DIN * H1;            // 131072
    const int n2 = H1 * H2;             // 32768
    const int n3 = K3DIM * O3;          // 24576
    if (idx < n1) {
        int c = idx / DIN, r = idx - c * DIN;
        w1t[idx] = f2bf(W1[r * H1 + c]);
    } else if (idx < n1 + n2) {
        int i2 = idx - n1;
        int c = i2 / H1, r = i2 - c * H1;
        w2t[i2] = f2bf(W2[r * H2 + c]);
    } else if (idx < n1 + n2 + n3) {
        int i3 = idx - n1 - n2;
        int c = i3 / K3DIM, r = i3 - c * K3DIM;
        w3t[i3] = f2bf(W3[r * O3 + c]);
    }
}

// ---------------------------------------------------------------- K1: h = x @ W1 + b1 (bf16 out)
// v5: BARRIER-FREE, LDS-FREE. 512 thr = 8 waves, each wave 32 rows x 128 cols
// (acc[2][8]). A loaded direct from x (fp32) + in-reg cvt; B direct from
// L2-hot W1^T. Ping-pong reg double-buffer, no __syncthreads anywhere.
__global__ __launch_bounds__(512, 2)
void gemm1_kernel(const float* __restrict__ x1, const float* __restrict__ x2,
                  const unsigned short* __restrict__ w1t, const float* __restrict__ b1,
                  unsigned short* __restrict__ h_out, float* __restrict__ stats) {
    const int t    = threadIdx.x;
    const int row0 = blockIdx.x * 128;          // 1024 blocks over 131072 rows
    const int inp  = row0 >> 16;                // 0 -> x1, 1 -> x2
    const float* xp = inp ? x2 : x1;
    const int r0 = row0 & (NROWS - 1);

    const int w = t >> 6, lane = t & 63;
    const int wr = w >> 1, wc = w & 1;          // 4 row-groups x 2 col-halves
    const int m = lane & 15, q = lane >> 4;
    const int rwA  = r0 + wr * 32;              // wave's x-row base
    const int col0 = wc * 128;                  // wave's col base

    const float* arow0 = xp + (size_t)(rwA + m) * DIN + q * 8;        // mi=0 rows
    const float* arow1 = xp + (size_t)(rwA + 16 + m) * DIN + q * 8;   // mi=1 rows
    const unsigned short* bbase = w1t + ((size_t)col0 + m) * DIN + q * 8;

    f32x4 acc[2][8] = {};
    float4 aA0, aA1, aA2, aA3; short8 bA[8];
    float4 aB0, aB1, aB2, aB3; short8 bB[8];

#define G1_LOAD(k0, A0, A1, A2, A3, BV)                                          \
    A0 = *reinterpret_cast<const float4*>(arow0 + (k0));                         \
    A1 = *reinterpret_cast<const float4*>(arow0 + (k0) + 4);                     \
    A2 = *reinterpret_cast<const float4*>(arow1 + (k0));                         \
    A3 = *reinterpret_cast<const float4*>(arow1 + (k0) + 4);                     \
    _Pragma("unroll")                                                            \
    for (int ni = 0; ni < 8; ++ni)                                               \
        BV[ni] = *reinterpret_cast<const short8*>(bbase + (size_t)ni * 16 * DIN + (k0));

#define G1_COMP(A0, A1, A2, A3, BV) {                                            \
    short8 af0, af1;                                                             \
    af0[0]=(short)f2bf(A0.x); af0[1]=(short)f2bf(A0.y);                          \
    af0[2]=(short)f2bf(A0.z); af0[3]=(short)f2bf(A0.w);                          \
    af0[4]=(short)f2bf(A1.x); af0[5]=(short)f2bf(A1.y);                          \
    af0[6]=(short)f2bf(A1.z); af0[7]=(short)f2bf(A1.w);                          \
    af1[0]=(short)f2bf(A2.x); af1[1]=(short)f2bf(A2.y);                          \
    af1[2]=(short)f2bf(A2.z); af1[3]=(short)f2bf(A2.w);                          \
    af1[4]=(short)f2bf(A3.x); af1[5]=(short)f2bf(A3.y);                          \
    af1[6]=(short)f2bf(A3.z); af1[7]=(short)f2bf(A3.w);                          \
    _Pragma("unroll")                                                            \
    for (int ni = 0; ni < 8; ++ni) {                                             \
        acc[0][ni] = __builtin_amdgcn_mfma_f32_16x16x32_bf16(af0, BV[ni], acc[0][ni], 0, 0, 0); \
        acc[1][ni] = __builtin_amdgcn_mfma_f32_16x16x32_bf16(af1, BV[ni], acc[1][ni], 0, 0, 0); \
    } }

    // prologue: step 0 into A-set
    G1_LOAD(0, aA0, aA1, aA2, aA3, bA);
    for (int kt2 = 0; kt2 < 8; ++kt2) {
        const int ke = kt2 * 64;
        G1_LOAD(ke + 32, aB0, aB1, aB2, aB3, bB);        // odd-step loads in flight
        G1_COMP(aA0, aA1, aA2, aA3, bA);                 // even-step compute
        if (kt2 < 7) { G1_LOAD(ke + 64, aA0, aA1, aA2, aA3, bA); }  // next even loads
        G1_COMP(aB0, aB1, aB2, aB3, bB);                 // odd-step compute
    }
#undef G1_LOAD
#undef G1_COMP

    // epilogue: h store + fused column sum / sumsq (fp32 pre-rounding values)
#pragma unroll
    for (int ni = 0; ni < 8; ++ni) {
        const int col = col0 + ni * 16 + m;
        const float bias = b1[col];
        float s = 0.f, ssq = 0.f;
#pragma unroll
        for (int mi = 0; mi < 2; ++mi) {
#pragma unroll
            for (int r = 0; r < 4; ++r) {
                int row = row0 + wr * 32 + mi * 16 + q * 4 + r;
                float v = acc[mi][ni][r] + bias;
                h_out[(size_t)row * H1 + col] = f2bf(v);
                s += v; ssq += v * v;
            }
        }
        // reduce over the 4 q-groups (lane bits 4,5): covers all 32 wave rows
        s   += __shfl_xor(s, 16);   s   += __shfl_xor(s, 32);
        ssq += __shfl_xor(ssq, 16); ssq += __shfl_xor(ssq, 32);
        if (q == 0) {
            atomicAdd(&stats[(inp * 2 + 0) * H1 + col], s);
            atomicAdd(&stats[(inp * 2 + 1) * H1 + col], ssq);
        }
    }
}

// ---------------------------------------------------------------- K2b: BN -> per-column affine
__global__ void bnparams_kernel(const float* __restrict__ stats, const float* __restrict__ gamma,
                                const float* __restrict__ beta_bn, float* __restrict__ ab) {
    int t = threadIdx.x;                // 512
    int inp = t >> 8, c = t & 255;
    float mean = stats[(inp * 2 + 0) * H1 + c] * (1.0f / NROWS);
    float ex2  = stats[(inp * 2 + 1) * H1 + c] * (1.0f / NROWS);
    float var  = ex2 - mean * mean;
    float a = gamma[c] * rsqrtf(var + 1e-5f);
    ab[(inp * 2 + 0) * H1 + c] = a;
    ab[(inp * 2 + 1) * H1 + c] = beta_bn[c] - a * mean;
}

// ---------------------------------------------------------------- K3a: z = relu(relu(BN(h)) @ W2 + b2)
// v5: BARRIER-FREE, LDS-FREE. 256 thr = 4 waves, each wave 32 rows x 128 cols
// (full H2 width -> h read once). BN-affine+relu fused into in-reg A-cvt;
// sc/sh read direct from ab (L2); B direct from L2-hot W2^T. Ping-pong regs.
__global__ __launch_bounds__(256, 2)
void gemm2_kernel(const unsigned short* __restrict__ h, const unsigned short* __restrict__ w2t,
                  const float* __restrict__ b2, const float* __restrict__ ab,
                  unsigned short* __restrict__ z) {
    const int t    = threadIdx.x;
    const int row0 = blockIdx.x * 128;          // 1024 blocks over 131072 rows
    const int inp  = row0 >> 16;
    const int w = t >> 6, lane = t & 63;
    const int m = lane & 15, q = lane >> 4;
    const int rw = row0 + w * 32;

    const unsigned short* h0 = h + (size_t)(rw + m) * H1 + q * 8;
    const unsigned short* h1 = h + (size_t)(rw + 16 + m) * H1 + q * 8;
    const unsigned short* bbase = w2t + (size_t)m * H1 + q * 8;
    const float* scp = ab + (inp * 2 + 0) * H1 + q * 8;
    const float* shp = ab + (inp * 2 + 1) * H1 + q * 8;

    f32x4 acc[2][8] = {};
    short8 hA0, hA1, bA[8]; float4 scA0, scA1, shA0, shA1;
    short8 hB0, hB1, bB[8]; float4 scB0, scB1, shB0, shB1;

#define G2_LOAD(k0, H0, H1v, SC0, SC1, SH0, SH1, BV)                             \
    H0  = *reinterpret_cast<const short8*>(h0 + (k0));                           \
    H1v = *reinterpret_cast<const short8*>(h1 + (k0));                           \
    SC0 = *reinterpret_cast<const float4*>(scp + (k0));                          \
    SC1 = *reinterpret_cast<const float4*>(scp + (k0) + 4);                      \
    SH0 = *reinterpret_cast<const float4*>(shp + (k0));                          \
    SH1 = *reinterpret_cast<const float4*>(shp + (k0) + 4);                      \
    _Pragma("unroll")                                                            \
    for (int ni = 0; ni < 8; ++ni)                                               \
        BV[ni] = *reinterpret_cast<const short8*>(bbase + (size_t)ni * 16 * H1 + (k0));

#define G2_CV(u, a, b) (short)f2bf(fmaxf((a) * bf2f((unsigned short)(u)) + (b), 0.f))
#define G2_COMP(H0, H1v, SC0, SC1, SH0, SH1, BV) {                               \
    short8 af0, af1;                                                             \
    af0[0]=G2_CV(H0[0],SC0.x,SH0.x); af0[1]=G2_CV(H0[1],SC0.y,SH0.y);            \
    af0[2]=G2_CV(H0[2],SC0.z,SH0.z); af0[3]=G2_CV(H0[3],SC0.w,SH0.w);            \
    af0[4]=G2_CV(H0[4],SC1.x,SH1.x); af0[5]=G2_CV(H0[5],SC1.y,SH1.y);            \
    af0[6]=G2_CV(H0[6],SC1.z,SH1.z); af0[7]=G2_CV(H0[7],SC1.w,SH1.w);            \
    af1[0]=G2_CV(H1v[0],SC0.x,SH0.x); af1[1]=G2_CV(H1v[1],SC0.y,SH0.y);          \
    af1[2]=G2_CV(H1v[2],SC0.z,SH0.z); af1[3]=G2_CV(H1v[3],SC0.w,SH0.w);          \
    af1[4]=G2_CV(H1v[4],SC1.x,SH1.x); af1[5]=G2_CV(H1v[5],SC1.y,SH1.y);          \
    af1[6]=G2_CV(H1v[6],SC1.z,SH1.z); af1[7]=G2_CV(H1v[7],SC1.w,SH1.w);          \
    _Pragma("unroll")                                                            \
    for (int ni = 0; ni < 8; ++ni) {                                             \
        acc[0][ni] = __builtin_amdgcn_mfma_f32_16x16x32_bf16(af0, BV[ni], acc[0][ni], 0, 0, 0); \
        acc[1][ni] = __builtin_amdgcn_mfma_f32_16x16x32_bf16(af1, BV[ni], acc[1][ni], 0, 0, 0); \
    } }

    G2_LOAD(0, hA0, hA1, scA0, scA1, shA0, shA1, bA);
    for (int kt2 = 0; kt2 < 4; ++kt2) {
        const int ke = kt2 * 64;
        G2_LOAD(ke + 32, hB0, hB1, scB0, scB1, shB0, shB1, bB);
        G2_COMP(hA0, hA1, scA0, scA1, shA0, shA1, bA);
        if (kt2 < 3) { G2_LOAD(ke + 64, hA0, hA1, scA0, scA1, shA0, shA1, bA); }
        G2_COMP(hB0, hB1, scB0, scB1, shB0, shB1, bB);
    }
#undef G2_LOAD
#undef G2_CV
#undef G2_COMP

#pragma unroll
    for (int ni = 0; ni < 8; ++ni) {
        const int col = ni * 16 + m;
        const float bias = b2[col];
#pragma unroll
        for (int mi = 0; mi < 2; ++mi) {
#pragma unroll
            for (int r = 0; r < 4; ++r) {
                int row = rw + mi * 16 + q * 4 + r;
                z[(size_t)row * H2 + col] = f2bf(fmaxf(acc[mi][ni][r] + bias, 0.f));
            }
        }
    }
}

// ---------------------------------------------------------------- K4: head (cosine + MLP + blend)
// v2 (unchanged): W3 direct from L2; LDS ~71KB -> 2 blocks/CU.
#define LDZ  136

__global__ __launch_bounds__(512, 2)
void head_kernel(const unsigned short* __restrict__ z, const unsigned short* __restrict__ w3t,
                 const float* __restrict__ b3, const float* __restrict__ w4,
                 const float* __restrict__ b4, const float* __restrict__ alpha,
                 const float* __restrict__ beta, float* __restrict__ out) {
    __shared__ __align__(16) unsigned short Z1[128 * LDZ];
    __shared__ __align__(16) unsigned short Z2[128 * LDZ];
    __shared__ float b3s[64], w4s[64];
    __shared__ float smath[128], slearn[128];

    const int t  = threadIdx.x;        // 512
    const int r0 = blockIdx.x * 128;

    {   // stage z1/z2 tiles: 128 rows x 128 bf16 each
        int r = t >> 2, seg = t & 3;
        const float4* f1 = reinterpret_cast<const float4*>(z + (size_t)(r0 + r) * H2 + seg * 32);
        const float4* f2 = reinterpret_cast<const float4*>(z + (size_t)(NROWS + r0 + r) * H2 + seg * 32);
        float4* d1 = reinterpret_cast<float4*>(&Z1[r * LDZ + seg * 32]);
        float4* d2 = reinterpret_cast<float4*>(&Z2[r * LDZ + seg * 32]);
        d1[0] = f1[0]; d1[1] = f1[1]; d1[2] = f1[2]; d1[3] = f1[3];
        d2[0] = f2[0]; d2[1] = f2[1]; d2[2] = f2[2]; d2[3] = f2[3];
    }
    if (t < 64) { b3s[t] = b3[t]; w4s[t] = w4[t]; }
    __syncthreads();

    {   // cosine: 4 threads per row
        int r = t >> 2, part = t & 3;
        float d = 0.f, s1 = 0.f, s2 = 0.f;
#pragma unroll
        for (int j = 0; j < 32; ++j) {
            int k = part * 32 + j;
            float a = bf2f(Z1[r * LDZ + k]);
            float b = bf2f(Z2[r * LDZ + k]);
            d += a * b; s1 += a * a; s2 += b * b;
        }
        d  += __shfl_xor(d, 1);  d  += __shfl_xor(d, 2);
        s1 += __shfl_xor(s1, 1); s1 += __shfl_xor(s1, 2);
        s2 += __shfl_xor(s2, 1); s2 += __shfl_xor(s2, 2);
        if (part == 0) {
            float inv1 = 1.f / fmaxf(sqrtf(s1), 1e-15f);
            float inv2 = 1.f / fmaxf(sqrtf(s2), 1e-15f);
            float sm = d * inv1 * inv2;
            smath[r] = fminf(fmaxf(sm, 0.f), 1.f);
        }
    }

    // MFMA over combined = [z1*z2 | |z1-z2| | z1+z2] @ W3 (B-frags direct from L2)
    const int wave = t >> 6, lane = t & 63;
    const int m = lane & 15, q = lane >> 4;
    const int wr = wave * 16;
    f32x4 acc[4] = {};
#pragma unroll
    for (int kb = 0; kb < 12; ++kb) {
        int seg = kb >> 2;
        int kl  = (kb & 3) * 32 + q * 8;
        short8 a1 = *reinterpret_cast<const short8*>(&Z1[(wr + m) * LDZ + kl]);
        short8 a2 = *reinterpret_cast<const short8*>(&Z2[(wr + m) * LDZ + kl]);
        short8 af;
#pragma unroll
        for (int j = 0; j < 8; ++j) {
            float v1 = bf2f((unsigned short)a1[j]);
            float v2 = bf2f((unsigned short)a2[j]);
            float v = (seg == 0) ? v1 * v2 : (seg == 1 ? fabsf(v1 - v2) : v1 + v2);
            af[j] = (short)f2bf(v);
        }
#pragma unroll
        for (int ni = 0; ni < 4; ++ni) {
            short8 bfr = *reinterpret_cast<const short8*>(
                w3t + (size_t)(ni * 16 + m) * K3DIM + kb * 32 + q * 8);
            acc[ni] = __builtin_amdgcn_mfma_f32_16x16x32_bf16(af, bfr, acc[ni], 0, 0, 0);
        }
    }
    float partial[4] = {0.f, 0.f, 0.f, 0.f};
#pragma unroll
    for (int ni = 0; ni < 4; ++ni) {
        int col = ni * 16 + m;
        float bias = b3s[col], w4v = w4s[col];
#pragma unroll
        for (int rg = 0; rg < 4; ++rg) {
            float v = fmaxf(acc[ni][rg] + bias, 0.f);
            partial[rg] += v * w4v;
        }
    }
#pragma unroll
    for (int rg = 0; rg < 4; ++rg) {
        float p = partial[rg];
        p += __shfl_xor(p, 1); p += __shfl_xor(p, 2);
        p += __shfl_xor(p, 4); p += __shfl_xor(p, 8);
        if (m == 0) slearn[wr + q * 4 + rg] = p + b4[0];
    }
    __syncthreads();
    if (t < 128) {
        float sl = slearn[t];
        float sig = 1.f / (1.f + expf(-sl));
        float f = alpha[0] * smath[t] + beta[0] * sig;
        out[r0 + t] = fminf(fmaxf(f, 0.f), 1.f);
    }
}

// ---------------------------------------------------------------- launch
extern "C" void kernel_launch(void* const* d_in, const int* in_sizes, int n_in,
                              void* d_out, int out_size, void* d_ws, size_t ws_size,
                              hipStream_t stream) {
    (void)in_sizes; (void)n_in; (void)out_size; (void)ws_size;
    const float* x1      = (const float*)d_in[0];
    const float* x2      = (const float*)d_in[1];
    const float* W1      = (const float*)d_in[2];
    const float* b1      = (const float*)d_in[3];
    const float* gamma   = (const float*)d_in[4];
    const float* beta_bn = (const float*)d_in[5];
    const float* W2      = (const float*)d_in[6];
    const float* b2      = (const float*)d_in[7];
    const float* W3      = (const float*)d_in[8];
    const float* b3      = (const float*)d_in[9];
    const float* W4      = (const float*)d_in[10];
    const float* b4      = (const float*)d_in[11];
    const float* alpha   = (const float*)d_in[12];
    const float* beta    = (const float*)d_in[13];
    float* out = (float*)d_out;

    char* ws = (char*)d_ws;
    unsigned short* h   = (unsigned short*)(ws);                  // 2*65536*256*2 = 67108864 B
    unsigned short* w1t = (unsigned short*)(ws + 67108864);       // 262144 B
    unsigned short* w2t = (unsigned short*)(ws + 67371008);       // 65536 B
    unsigned short* w3t = (unsigned short*)(ws + 67436544);       // 49152 B
    float*          stats = (float*)(ws + 67485696);              // 4096 B
    float*          ab    = (float*)(ws + 67489792);              // 4096 B
    unsigned short* z   = (unsigned short*)(ws + 67493888);       // 33554432 B

    (void)hipMemsetAsync(stats, 0, 4096, stream);
    transpose3_kernel<<<(DIN * H1 + H1 * H2 + K3DIM * O3 + 255) / 256, 256, 0, stream>>>(
        W1, W2, W3, w1t, w2t, w3t);
    gemm1_kernel<<<1024, 512, 0, stream>>>(x1, x2, w1t, b1, h, stats);
    bnparams_kernel<<<1, 512, 0, stream>>>(stats, gamma, beta_bn, ab);
    gemm2_kernel<<<1024, 256, 0, stream>>>(h, w2t, b2, ab, z);
    head_kernel<<<512, 512, 0, stream>>>(z, w3t, b3, W4, b4, alpha, beta, out);
}

// Round 8
// 377.509 us; speedup vs baseline: 1.4347x; 1.4347x over previous
//
#include <hip/hip_runtime.h>
#include <hip/hip_bf16.h>
#include <math.h>

#define NROWS 65536
#define DIN   512
#define H1    256
#define H2    128
#define K3DIM 384
#define O3    64

typedef short  short8  __attribute__((ext_vector_type(8)));
typedef float  f32x4   __attribute__((ext_vector_type(4)));

// fp32 -> bf16 bits, round-to-nearest-even
__device__ __forceinline__ unsigned short f2bf(float f) {
    union { float f; unsigned int i; } v; v.f = f;
    unsigned int r = (v.i + 0x7fffu + ((v.i >> 16) & 1u)) >> 16;
    return (unsigned short)r;
}
// bf16 bits -> fp32 (exact)
__device__ __forceinline__ float bf2f(unsigned short u) {
    union { unsigned int i; float f; } v; v.i = ((unsigned int)u) << 16;
    return v.f;
}

// async global->LDS, 16B per lane. lds ptr must be wave-uniform (HW adds lane*16).
typedef const __attribute__((address_space(1))) unsigned int* gas1_t;
typedef __attribute__((address_space(3))) unsigned int* las3_t;
__device__ __forceinline__ void gload_lds16(const void* g, void* l) {
    __builtin_amdgcn_global_load_lds((gas1_t)g, (las3_t)l, 16, 0, 0);
}

// ---------------------------------------------------------------- K0: all three W -> W^T bf16
__global__ void transpose3_kernel(const float* __restrict__ W1, const float* __restrict__ W2,
                                  const float* __restrict__ W3,
                                  unsigned short* __restrict__ w1t, unsigned short* __restrict__ w2t,
                                  unsigned short* __restrict__ w3t) {
    int idx = blockIdx.x * 256 + threadIdx.x;
    const int n1 = DIN * H1;            // 131072
    const int n2 = H1 * H2;             // 32768
    const int n3 = K3DIM * O3;          // 24576
    if (idx < n1) {
        int c = idx / DIN, r = idx - c * DIN;
        w1t[idx] = f2bf(W1[r * H1 + c]);
    } else if (idx < n1 + n2) {
        int i2 = idx - n1;
        int c = i2 / H1, r = i2 - c * H1;
        w2t[i2] = f2bf(W2[r * H2 + c]);
    } else if (idx < n1 + n2 + n3) {
        int i3 = idx - n1 - n2;
        int c = i3 / K3DIM, r = i3 - c * K3DIM;
        w3t[i3] = f2bf(W3[r * O3 + c]);
    }
}

// ---------------------------------------------------------------- K1: h = x @ W1 + b1 (bf16 out)
// v6: measured-best 1-phase skeleton (R1=136us) + BK=64 (8 iters, 2x loads in
// flight per drain) + XOR-swizzled B (pre-swizzled global src, linear LDS,
// swizzled read) + padded A stride. Single-buffered, full drains, race-free.
#define LDA1P 72   // padded A stride in elems (144B rows: m-lanes spread over banks)

__global__ __launch_bounds__(256, 2)
void gemm1_kernel(const float* __restrict__ x1, const float* __restrict__ x2,
                  const unsigned short* __restrict__ w1t, const float* __restrict__ b1,
                  unsigned short* __restrict__ h_out, float* __restrict__ stats) {
    __shared__ __align__(1024) unsigned short Bl[256 * 64];     // 32 KB (linear; swizzled content)
    __shared__ __align__(16)   unsigned short Al[64 * LDA1P];   //  9 KB (padded)
    const int t    = threadIdx.x;
    const int row0 = blockIdx.x * 64;           // 2048 blocks over 131072 rows
    const int inp  = row0 >> 16;                // 0 -> x1, 1 -> x2
    const float* xp = inp ? x2 : x1;
    const int r0 = row0 & (NROWS - 1);

    const int w = t >> 6, lane = t & 63;        // wave w owns cols w*64..w*64+64
    const int m = lane & 15, q = lane >> 4;

    // B gload source mapping: chunk = 8 rows x 64 k (1KB). Swizzle: 16B slot
    // (lane&7) in LDS receives logical k-slot (lane&7)^(row&7).
    const int brow_l = lane >> 3;               // row within 8-row chunk
    const int bslot  = (lane & 7) ^ brow_l;     // pre-swizzled source k-slot
    // A staging: thread -> (row, 16-elem k-segment)
    const int arow  = t >> 2;                   // 0..63
    const int akseg = (t & 3) * 16;             // 0/16/32/48

    f32x4 acc[4][4] = {};                       // [mi][ni]

    for (int kt = 0; kt < 8; ++kt) {
        const int k0 = kt * 64;
        __syncthreads();                        // prev iter's readers done
        // stage B: 256 rows x 64 k via 32 chunks (8 per wave), swizzled source
#pragma unroll
        for (int i = 0; i < 8; ++i) {
            int c = w * 8 + i;
            gload_lds16(w1t + (size_t)(c * 8 + brow_l) * DIN + k0 + bslot * 8,
                        &Bl[c * 512]);
        }
        // stage A: 64 rows x 64 k fp32 -> bf16, padded stride
        {
            const float* asrc = xp + (size_t)(r0 + arow) * DIN + k0 + akseg;
            float4 v0 = *reinterpret_cast<const float4*>(asrc);
            float4 v1 = *reinterpret_cast<const float4*>(asrc + 4);
            float4 v2 = *reinterpret_cast<const float4*>(asrc + 8);
            float4 v3 = *reinterpret_cast<const float4*>(asrc + 12);
            unsigned short ob[16] __attribute__((aligned(16)));
            ob[0]=f2bf(v0.x); ob[1]=f2bf(v0.y); ob[2]=f2bf(v0.z); ob[3]=f2bf(v0.w);
            ob[4]=f2bf(v1.x); ob[5]=f2bf(v1.y); ob[6]=f2bf(v1.z); ob[7]=f2bf(v1.w);
            ob[8]=f2bf(v2.x); ob[9]=f2bf(v2.y); ob[10]=f2bf(v2.z); ob[11]=f2bf(v2.w);
            ob[12]=f2bf(v3.x); ob[13]=f2bf(v3.y); ob[14]=f2bf(v3.z); ob[15]=f2bf(v3.w);
            *reinterpret_cast<float4*>(&Al[arow * LDA1P + akseg])     = *reinterpret_cast<float4*>(ob);
            *reinterpret_cast<float4*>(&Al[arow * LDA1P + akseg + 8]) = *reinterpret_cast<float4*>(ob + 8);
        }
        __syncthreads();                        // drains vmcnt(0)+lgkmcnt: tile visible
        // compute: two BK=32 sub-steps (keeps frag regs modest)
#pragma unroll
        for (int s = 0; s < 2; ++s) {
            short8 af[4], bfr[4];
#pragma unroll
            for (int mi = 0; mi < 4; ++mi)
                af[mi] = *reinterpret_cast<const short8*>(&Al[(mi * 16 + m) * LDA1P + s * 32 + q * 8]);
#pragma unroll
            for (int ni = 0; ni < 4; ++ni) {
                int rb = w * 64 + ni * 16 + m;
                int kb = (q * 16 + s * 64) ^ ((m & 7) << 4);   // swizzled read
                bfr[ni] = *reinterpret_cast<const short8*>(
                    reinterpret_cast<const char*>(Bl) + rb * 128 + kb);
            }
#pragma unroll
            for (int mi = 0; mi < 4; ++mi)
#pragma unroll
                for (int ni = 0; ni < 4; ++ni)
                    acc[mi][ni] = __builtin_amdgcn_mfma_f32_16x16x32_bf16(af[mi], bfr[ni], acc[mi][ni], 0, 0, 0);
        }
    }

    // epilogue: h store + fused column sum / sumsq (fp32 pre-rounding values)
#pragma unroll
    for (int ni = 0; ni < 4; ++ni) {
        const int col = w * 64 + ni * 16 + m;
        const float bias = b1[col];
        float s = 0.f, ssq = 0.f;
#pragma unroll
        for (int mi = 0; mi < 4; ++mi) {
#pragma unroll
            for (int r = 0; r < 4; ++r) {
                int row = row0 + mi * 16 + q * 4 + r;
                float v = acc[mi][ni][r] + bias;
                h_out[(size_t)row * H1 + col] = f2bf(v);
                s += v; ssq += v * v;
            }
        }
        s   += __shfl_xor(s, 16);   s   += __shfl_xor(s, 32);
        ssq += __shfl_xor(ssq, 16); ssq += __shfl_xor(ssq, 32);
        if (q == 0) {
            atomicAdd(&stats[(inp * 2 + 0) * H1 + col], s);
            atomicAdd(&stats[(inp * 2 + 1) * H1 + col], ssq);
        }
    }
}

// ---------------------------------------------------------------- K2b: BN -> per-column affine
__global__ void bnparams_kernel(const float* __restrict__ stats, const float* __restrict__ gamma,
                                const float* __restrict__ beta_bn, float* __restrict__ ab) {
    int t = threadIdx.x;                // 512
    int inp = t >> 8, c = t & 255;
    float mean = stats[(inp * 2 + 0) * H1 + c] * (1.0f / NROWS);
    float ex2  = stats[(inp * 2 + 1) * H1 + c] * (1.0f / NROWS);
    float var  = ex2 - mean * mean;
    float a = gamma[c] * rsqrtf(var + 1e-5f);
    ab[(inp * 2 + 0) * H1 + c] = a;
    ab[(inp * 2 + 1) * H1 + c] = beta_bn[c] - a * mean;
}

// ---------------------------------------------------------------- K3a: z = relu(relu(BN(h)) @ W2 + b2)
// v6: same upgraded skeleton as gemm1: BK=64 (4 iters), per-tile B via
// swizzled gload_lds (16KB, not full 64KB), padded A (BN+relu fused in cvt).
// LDS 36KB -> 4 blocks/CU (was 76KB -> 2).
__global__ __launch_bounds__(256, 2)
void gemm2_kernel(const unsigned short* __restrict__ h, const unsigned short* __restrict__ w2t,
                  const float* __restrict__ b2, const float* __restrict__ ab,
                  unsigned short* __restrict__ z) {
    __shared__ __align__(1024) unsigned short B2l[128 * 64];    // 16 KB (swizzled content)
    __shared__ __align__(16)   unsigned short A2l[128 * LDA1P]; // 18 KB (padded)
    __shared__ float sc[H1], sh[H1];
    const int t  = threadIdx.x;
    const int m0 = blockIdx.x * 128;            // 1024 blocks
    const int inp = m0 >> 16;
    sc[t] = ab[(inp * 2 + 0) * H1 + t];
    sh[t] = ab[(inp * 2 + 1) * H1 + t];

    const int w = t >> 6, lane = t & 63;
    const int wm = w >> 1, wn = w & 1;
    const int m = lane & 15, q = lane >> 4;

    const int brow_l = lane >> 3;
    const int bslot  = (lane & 7) ^ brow_l;
    const int arow  = t >> 1;                   // 0..127
    const int akseg = (t & 1) * 32;             // 0/32

    f32x4 acc[4][4] = {};

    for (int kt = 0; kt < 4; ++kt) {
        const int k0 = kt * 64;
        __syncthreads();                        // prev readers done (also covers sc/sh)
        // stage B: 128 rows x 64 k via 16 chunks (4 per wave), swizzled source
#pragma unroll
        for (int i = 0; i < 4; ++i) {
            int c = w * 4 + i;
            gload_lds16(w2t + (size_t)(c * 8 + brow_l) * H1 + k0 + bslot * 8,
                        &B2l[c * 512]);
        }
        // stage A: 128 rows x 64 k from h, BN-affine + relu fused, padded
        {
            const unsigned short* asrc = h + (size_t)(m0 + arow) * H1 + k0 + akseg;
            short8 v0 = *reinterpret_cast<const short8*>(asrc);
            short8 v1 = *reinterpret_cast<const short8*>(asrc + 8);
            short8 v2 = *reinterpret_cast<const short8*>(asrc + 16);
            short8 v3 = *reinterpret_cast<const short8*>(asrc + 24);
            unsigned short ob[32] __attribute__((aligned(16)));
#pragma unroll
            for (int j = 0; j < 8; ++j) {
                int k = k0 + akseg + j;
                ob[j]      = f2bf(fmaxf(sc[k]      * bf2f((unsigned short)v0[j]) + sh[k],      0.f));
                ob[j + 8]  = f2bf(fmaxf(sc[k + 8]  * bf2f((unsigned short)v1[j]) + sh[k + 8],  0.f));
                ob[j + 16] = f2bf(fmaxf(sc[k + 16] * bf2f((unsigned short)v2[j]) + sh[k + 16], 0.f));
                ob[j + 24] = f2bf(fmaxf(sc[k + 24] * bf2f((unsigned short)v3[j]) + sh[k + 24], 0.f));
            }
#pragma unroll
            for (int i = 0; i < 4; ++i)
                *reinterpret_cast<float4*>(&A2l[arow * LDA1P + akseg + i * 8]) =
                    *reinterpret_cast<float4*>(ob + i * 8);
        }
        __syncthreads();                        // tile visible
#pragma unroll
        for (int s = 0; s < 2; ++s) {
            short8 af[4], bfr[4];
#pragma unroll
            for (int mi = 0; mi < 4; ++mi)
                af[mi] = *reinterpret_cast<const short8*>(&A2l[(wm * 64 + mi * 16 + m) * LDA1P + s * 32 + q * 8]);
#pragma unroll
            for (int ni = 0; ni < 4; ++ni) {
                int rb = wn * 64 + ni * 16 + m;
                int kb = (q * 16 + s * 64) ^ ((m & 7) << 4);
                bfr[ni] = *reinterpret_cast<const short8*>(
                    reinterpret_cast<const char*>(B2l) + rb * 128 + kb);
            }
#pragma unroll
            for (int mi = 0; mi < 4; ++mi)
#pragma unroll
                for (int ni = 0; ni < 4; ++ni)
                    acc[mi][ni] = __builtin_amdgcn_mfma_f32_16x16x32_bf16(af[mi], bfr[ni], acc[mi][ni], 0, 0, 0);
        }
    }
#pragma unroll
    for (int mi = 0; mi < 4; ++mi)
#pragma unroll
        for (int ni = 0; ni < 4; ++ni) {
            int col = wn * 64 + ni * 16 + m;
            float bias = b2[col];
#pragma unroll
            for (int r = 0; r < 4; ++r) {
                int row = m0 + wm * 64 + mi * 16 + q * 4 + r;
                z[(size_t)row * H2 + col] = f2bf(fmaxf(acc[mi][ni][r] + bias, 0.f));
            }
        }
}

// ---------------------------------------------------------------- K4: head (cosine + MLP + blend)
// v2 (unchanged): W3 direct from L2; LDS ~71KB -> 2 blocks/CU.
#define LDZ  136

__global__ __launch_bounds__(512, 2)
void head_kernel(const unsigned short* __restrict__ z, const unsigned short* __restrict__ w3t,
                 const float* __restrict__ b3, const float* __restrict__ w4,
                 const float* __restrict__ b4, const float* __restrict__ alpha,
                 const float* __restrict__ beta, float* __restrict__ out) {
    __shared__ __align__(16) unsigned short Z1[128 * LDZ];
    __shared__ __align__(16) unsigned short Z2[128 * LDZ];
    __shared__ float b3s[64], w4s[64];
    __shared__ float smath[128], slearn[128];

    const int t  = threadIdx.x;        // 512
    const int r0 = blockIdx.x * 128;

    {   // stage z1/z2 tiles: 128 rows x 128 bf16 each
        int r = t >> 2, seg = t & 3;
        const float4* f1 = reinterpret_cast<const float4*>(z + (size_t)(r0 + r) * H2 + seg * 32);
        const float4* f2 = reinterpret_cast<const float4*>(z + (size_t)(NROWS + r0 + r) * H2 + seg * 32);
        float4* d1 = reinterpret_cast<float4*>(&Z1[r * LDZ + seg * 32]);
        float4* d2 = reinterpret_cast<float4*>(&Z2[r * LDZ + seg * 32]);
        d1[0] = f1[0]; d1[1] = f1[1]; d1[2] = f1[2]; d1[3] = f1[3];
        d2[0] = f2[0]; d2[1] = f2[1]; d2[2] = f2[2]; d2[3] = f2[3];
    }
    if (t < 64) { b3s[t] = b3[t]; w4s[t] = w4[t]; }
    __syncthreads();

    {   // cosine: 4 threads per row
        int r = t >> 2, part = t & 3;
        float d = 0.f, s1 = 0.f, s2 = 0.f;
#pragma unroll
        for (int j = 0; j < 32; ++j) {
            int k = part * 32 + j;
            float a = bf2f(Z1[r * LDZ + k]);
            float b = bf2f(Z2[r * LDZ + k]);
            d += a * b; s1 += a * a; s2 += b * b;
        }
        d  += __shfl_xor(d, 1);  d  += __shfl_xor(d, 2);
        s1 += __shfl_xor(s1, 1); s1 += __shfl_xor(s1, 2);
        s2 += __shfl_xor(s2, 1); s2 += __shfl_xor(s2, 2);
        if (part == 0) {
            float inv1 = 1.f / fmaxf(sqrtf(s1), 1e-15f);
            float inv2 = 1.f / fmaxf(sqrtf(s2), 1e-15f);
            float sm = d * inv1 * inv2;
            smath[r] = fminf(fmaxf(sm, 0.f), 1.f);
        }
    }

    // MFMA over combined = [z1*z2 | |z1-z2| | z1+z2] @ W3 (B-frags direct from L2)
    const int wave = t >> 6, lane = t & 63;
    const int m = lane & 15, q = lane >> 4;
    const int wr = wave * 16;
    f32x4 acc[4] = {};
#pragma unroll
    for (int kb = 0; kb < 12; ++kb) {
        int seg = kb >> 2;
        int kl  = (kb & 3) * 32 + q * 8;
        short8 a1 = *reinterpret_cast<const short8*>(&Z1[(wr + m) * LDZ + kl]);
        short8 a2 = *reinterpret_cast<const short8*>(&Z2[(wr + m) * LDZ + kl]);
        short8 af;
#pragma unroll
        for (int j = 0; j < 8; ++j) {
            float v1 = bf2f((unsigned short)a1[j]);
            float v2 = bf2f((unsigned short)a2[j]);
            float v = (seg == 0) ? v1 * v2 : (seg == 1 ? fabsf(v1 - v2) : v1 + v2);
            af[j] = (short)f2bf(v);
        }
#pragma unroll
        for (int ni = 0; ni < 4; ++ni) {
            short8 bfr = *reinterpret_cast<const short8*>(
                w3t + (size_t)(ni * 16 + m) * K3DIM + kb * 32 + q * 8);
            acc[ni] = __builtin_amdgcn_mfma_f32_16x16x32_bf16(af, bfr, acc[ni], 0, 0, 0);
        }
    }
    float partial[4] = {0.f, 0.f, 0.f, 0.f};
#pragma unroll
    for (int ni = 0; ni < 4; ++ni) {
        int col = ni * 16 + m;
        float bias = b3s[col], w4v = w4s[col];
#pragma unroll
        for (int rg = 0; rg < 4; ++rg) {
            float v = fmaxf(acc[ni][rg] + bias, 0.f);
            partial[rg] += v * w4v;
        }
    }
#pragma unroll
    for (int rg = 0; rg < 4; ++rg) {
        float p = partial[rg];
        p += __shfl_xor(p, 1); p += __shfl_xor(p, 2);
        p += __shfl_xor(p, 4); p += __shfl_xor(p, 8);
        if (m == 0) slearn[wr + q * 4 + rg] = p + b4[0];
    }
    __syncthreads();
    if (t < 128) {
        float sl = slearn[t];
        float sig = 1.f / (1.f + expf(-sl));
        float f = alpha[0] * smath[t] + beta[0] * sig;
        out[r0 + t] = fminf(fmaxf(f, 0.f), 1.f);
    }
}

// ---------------------------------------------------------------- launch
extern "C" void kernel_launch(void* const* d_in, const int* in_sizes, int n_in,
                              void* d_out, int out_size, void* d_ws, size_t ws_size,
                              hipStream_t stream) {
    (void)in_sizes; (void)n_in; (void)out_size; (void)ws_size;
    const float* x1      = (const float*)d_in[0];
    const float* x2      = (const float*)d_in[1];
    const float* W1      = (const float*)d_in[2];
    const float* b1      = (const float*)d_in[3];
    const float* gamma   = (const float*)d_in[4];
    const float* beta_bn = (const float*)d_in[5];
    const float* W2      = (const float*)d_in[6];
    const float* b2      = (const float*)d_in[7];
    const float* W3      = (const float*)d_in[8];
    const float* b3      = (const float*)d_in[9];
    const float* W4      = (const float*)d_in[10];
    const float* b4      = (const float*)d_in[11];
    const float* alpha   = (const float*)d_in[12];
    const float* beta    = (const float*)d_in[13];
    float* out = (float*)d_out;

    char* ws = (char*)d_ws;
    unsigned short* h   = (unsigned short*)(ws);                  // 2*65536*256*2 = 67108864 B
    unsigned short* w1t = (unsigned short*)(ws + 67108864);       // 262144 B
    unsigned short* w2t = (unsigned short*)(ws + 67371008);       // 65536 B
    unsigned short* w3t = (unsigned short*)(ws + 67436544);       // 49152 B
    float*          stats = (float*)(ws + 67485696);              // 4096 B
    float*          ab    = (float*)(ws + 67489792);              // 4096 B
    unsigned short* z   = (unsigned short*)(ws + 67493888);       // 33554432 B

    (void)hipMemsetAsync(stats, 0, 4096, stream);
    transpose3_kernel<<<(DIN * H1 + H1 * H2 + K3DIM * O3 + 255) / 256, 256, 0, stream>>>(
        W1, W2, W3, w1t, w2t, w3t);
    gemm1_kernel<<<2048, 256, 0, stream>>>(x1, x2, w1t, b1, h, stats);
    bnparams_kernel<<<1, 512, 0, stream>>>(stats, gamma, beta_bn, ab);
    gemm2_kernel<<<1024, 256, 0, stream>>>(h, w2t, b2, ab, z);
    head_kernel<<<512, 512, 0, stream>>>(z, w3t, b3, W4, b4, alpha, beta, out);
}